// Round 1
// baseline (365.283 us; speedup 1.0000x reference)
//
#include <hip/hip_runtime.h>

// SCSSystem: strided gather (stride-2 subsample) * weight -> scatter to target grid.
// Key structural fact (verified from _stride_indices math): target_indices is a
// bijection onto [0, TH*TW) (identity here), so the scatter-add has no duplicate
// targets -> plain stores, no atomics, no zero-init (full coverage).
__global__ void scs_gather_kernel(const float* __restrict__ src,
                                  const float* __restrict__ wts,
                                  const int* __restrict__ sidx,
                                  const int* __restrict__ tidx,
                                  const int* __restrict__ th_p,
                                  const int* __restrict__ tw_p,
                                  float* __restrict__ out,
                                  int N,
                                  long long src_total,
                                  long long out_total) {
    int k = blockIdx.x * blockDim.x + threadIdx.x;
    if (k >= N) return;

    // Scalar params live in device memory (harness passes python ints as
    // 1-element arrays). These loads are wave-uniform and L2-resident.
    const int TO = th_p[0] * tw_p[0];          // target plane size
    const int B  = (int)(out_total / TO);      // batch
    const long long SB = src_total / B;        // source plane size

    const int   s = sidx[k];
    const int   t = tidx[k];
    const float w = wts[k];

    const float* __restrict__ sp = src + s;
    float* __restrict__ op = out + t;
    #pragma unroll 4
    for (int b = 0; b < B; ++b) {
        op[(long long)b * TO] = sp[(long long)b * SB] * w;
    }
}

extern "C" void kernel_launch(void* const* d_in, const int* in_sizes, int n_in,
                              void* d_out, int out_size, void* d_ws, size_t ws_size,
                              hipStream_t stream) {
    const float* src  = (const float*)d_in[0];
    const float* wts  = (const float*)d_in[1];
    const int*   sidx = (const int*)d_in[2];
    const int*   tidx = (const int*)d_in[3];
    const int*   th_p = (const int*)d_in[4];
    const int*   tw_p = (const int*)d_in[5];
    float*       out  = (float*)d_out;

    const int N = in_sizes[2];                  // number of connections
    const long long src_total = in_sizes[0];    // B * SH * SW
    const long long out_total = out_size;       // B * TH * TW

    const int threads = 256;
    const int blocks = (N + threads - 1) / threads;
    scs_gather_kernel<<<blocks, threads, 0, stream>>>(
        src, wts, sidx, tidx, th_p, tw_p, out, N, src_total, out_total);
}

// Round 2
// 362.656 us; speedup vs baseline: 1.0072x; 1.0072x over previous
//
#include <hip/hip_runtime.h>

// SCSSystem: stride-2 gather * weight -> identity scatter (bijective targets:
// no duplicates -> plain stores, no atomics, no zero-init, full coverage).
//
// v2: 4 outputs per thread. Fast path (runtime-verified per thread, uniform
// for this input): source indices are {s, s+2, s+4, s+6} with s % 4 == 0 and
// target indices {t, t+1, t+2, t+3} with t % 4 == 0 -> two float4 src loads,
// one float4 store, int4/float4 metadata loads. Fallback: scalar per element.
__global__ void scs_gather_v2(const float* __restrict__ src,
                              const float* __restrict__ wts,
                              const int* __restrict__ sidx,
                              const int* __restrict__ tidx,
                              const int* __restrict__ th_p,
                              const int* __restrict__ tw_p,
                              float* __restrict__ out,
                              int N,
                              long long src_total,
                              long long out_total) {
    const int TO = th_p[0] * tw_p[0];          // target plane size
    const int B  = (int)(out_total / TO);      // batch
    const long long SB = src_total / B;        // source plane size

    const int k0 = (blockIdx.x * blockDim.x + threadIdx.x) * 4;
    if (k0 >= N) return;

    if (k0 + 3 < N) {
        const int4   sv = *reinterpret_cast<const int4*>(sidx + k0);
        const int4   tv = *reinterpret_cast<const int4*>(tidx + k0);
        const float4 wv = *reinterpret_cast<const float4*>(wts + k0);

        const bool s_ok = ((sv.x & 3) == 0) && (sv.y == sv.x + 2) &&
                          (sv.z == sv.x + 4) && (sv.w == sv.x + 6) &&
                          ((SB & 3) == 0);
        const bool t_ok = ((tv.x & 3) == 0) && (tv.y == tv.x + 1) &&
                          (tv.z == tv.x + 2) && (tv.w == tv.x + 3) &&
                          ((TO & 3) == 0);

        if (s_ok && t_ok) {
            const float* sp = src + sv.x;
            float*       op = out + tv.x;
            #pragma unroll 4
            for (int b = 0; b < B; ++b) {
                const float4 a = *reinterpret_cast<const float4*>(sp + (long long)b * SB);
                const float4 c = *reinterpret_cast<const float4*>(sp + (long long)b * SB + 4);
                float4 r;
                r.x = a.x * wv.x;   // src[s+0]
                r.y = a.z * wv.y;   // src[s+2]
                r.z = c.x * wv.z;   // src[s+4]
                r.w = c.z * wv.w;   // src[s+6]
                *reinterpret_cast<float4*>(op + (long long)b * TO) = r;
            }
            return;
        }
    }

    // Fallback: scalar, handles tail and any non-conforming index pattern.
    for (int m = 0; m < 4; ++m) {
        const int k = k0 + m;
        if (k >= N) break;
        const int   s = sidx[k];
        const int   t = tidx[k];
        const float w = wts[k];
        for (int b = 0; b < B; ++b) {
            out[(long long)b * TO + t] = src[(long long)b * SB + s] * w;
        }
    }
}

extern "C" void kernel_launch(void* const* d_in, const int* in_sizes, int n_in,
                              void* d_out, int out_size, void* d_ws, size_t ws_size,
                              hipStream_t stream) {
    const float* src  = (const float*)d_in[0];
    const float* wts  = (const float*)d_in[1];
    const int*   sidx = (const int*)d_in[2];
    const int*   tidx = (const int*)d_in[3];
    const int*   th_p = (const int*)d_in[4];
    const int*   tw_p = (const int*)d_in[5];
    float*       out  = (float*)d_out;

    const int N = in_sizes[2];
    const long long src_total = in_sizes[0];
    const long long out_total = out_size;

    const int threads = 256;
    const int nvec = (N + 3) / 4;
    const int blocks = (nvec + threads - 1) / threads;
    scs_gather_v2<<<blocks, threads, 0, stream>>>(
        src, wts, sidx, tidx, th_p, tw_p, out, N, src_total, out_total);
}